// Round 1
// baseline (1079.596 us; speedup 1.0000x reference)
//
#include <hip/hip_runtime.h>
#include <math.h>

#define TPB 256

// Fused: conv3d(3x3x3,pad1) -> spline(KAN cubic) + SiLU -> BN(eval affine) -> maxpool 2x2x2
// One thread per POOLED output voxel. Block handles one (n, cout) pair + a tile of
// 256 pooled voxels; conv weights for that cout staged in LDS (broadcast reads).
__global__ __launch_bounds__(TPB) void spline_block_kernel(
    const float* __restrict__ x,    // [N, Cin, D, H, W]
    const float* __restrict__ cw,   // [Cout, Cin, 3,3,3]
    const float* __restrict__ cb,   // [Cout]
    const float* __restrict__ knots,// [10]
    const float* __restrict__ sw,   // [Cout, 10]
    const float* __restrict__ w1,   // [Cout]
    const float* __restrict__ w2,   // [Cout]
    const float* __restrict__ g,    // [Cout]
    const float* __restrict__ beta, // [Cout]
    float* __restrict__ out,        // [N, Cout, D/2, H/2, W/2]
    int N, int Cin, int Cout, int D, int H, int W)
{
    __shared__ float lds_w[64 * 27];   // max Cin=64 here
    const int nc  = blockIdx.x;
    const int c   = nc % Cout;
    const int n   = nc / Cout;
    const int tid = threadIdx.x;

    const int nw = Cin * 27;
    for (int i = tid; i < nw; i += TPB)
        lds_w[i] = cw[c * nw + i];
    __syncthreads();

    const int PD = D >> 1, PH = H >> 1, PW = W >> 1;
    const int total = PD * PH * PW;
    const int vox = blockIdx.y * TPB + tid;
    if (vox >= total) return;

    const int pw = vox % PW;
    int t = vox / PW;
    const int ph = t % PH;
    const int pd = t / PH;

    const float bias = cb[c];
    float acc[8];
#pragma unroll
    for (int i = 0; i < 8; i++) acc[i] = bias;

    const int d0 = 2 * pd - 1, h0 = 2 * ph - 1, w0 = 2 * pw - 1;

    for (int ci = 0; ci < Cin; ci++) {
        const float* xc = x + ((size_t)(n * Cin + ci)) * D * H * W;
        // 4x4x4 input region covering the 2x2x2 conv outputs' receptive fields
        float r[64];
#pragma unroll
        for (int dz = 0; dz < 4; dz++)
#pragma unroll
        for (int dy = 0; dy < 4; dy++)
#pragma unroll
        for (int dx = 0; dx < 4; dx++) {
            const int dd = d0 + dz, hh = h0 + dy, ww = w0 + dx;
            const bool ok = ((unsigned)dd < (unsigned)D) &
                            ((unsigned)hh < (unsigned)H) &
                            ((unsigned)ww < (unsigned)W);
            r[(dz * 4 + dy) * 4 + dx] = ok ? xc[(dd * H + hh) * W + ww] : 0.0f;
        }
        const float* wc = lds_w + ci * 27;
#pragma unroll
        for (int kd = 0; kd < 3; kd++)
#pragma unroll
        for (int kh = 0; kh < 3; kh++)
#pragma unroll
        for (int kw = 0; kw < 3; kw++) {
            const float wv = wc[(kd * 3 + kh) * 3 + kw];
#pragma unroll
            for (int od = 0; od < 2; od++)
#pragma unroll
            for (int oh = 0; oh < 2; oh++)
#pragma unroll
            for (int ow = 0; ow < 2; ow++)
                acc[(od * 2 + oh) * 2 + ow] =
                    fmaf(wv, r[((od + kd) * 4 + (oh + kh)) * 4 + (ow + kw)],
                         acc[(od * 2 + oh) * 2 + ow]);
        }
    }

    // spline + SiLU + BN affine + max-pool over the 8 conv outputs
    float kn[10], sc[10];
#pragma unroll
    for (int k = 0; k < 10; k++) { kn[k] = knots[k]; sc[k] = sw[c * 10 + k]; }
    const float W1 = w1[c], W2 = w2[c];
    const float scale = g[c] * rsqrtf(1.0f + 1e-5f);
    const float bb = beta[c];

    float m = -INFINITY;
#pragma unroll
    for (int i = 0; i < 8; i++) {
        const float y = acc[i];
        float sp = 0.0f;
#pragma unroll
        for (int k = 0; k < 10; k++) {
            const float tt = fmaxf(y - kn[k], 0.0f);
            sp = fmaf(tt * tt * tt, sc[k], sp);
        }
        const float silu = y / (1.0f + expf(-y));   // y * sigmoid(y)
        const float o = fmaf(W1 * sp + W2 * silu, scale, bb);
        m = fmaxf(m, o);
    }
    out[(size_t)nc * total + vox] = m;
}

// Global average pool: one wave per (n,c); S = spatial size
__global__ __launch_bounds__(64) void mean_kernel(
    const float* __restrict__ h, float* __restrict__ out, int S)
{
    const int nc = blockIdx.x;
    const int lane = threadIdx.x;
    const float* p = h + (size_t)nc * S;
    float s = 0.0f;
    for (int i = lane; i < S; i += 64) s += p[i];
#pragma unroll
    for (int off = 32; off > 0; off >>= 1) s += __shfl_down(s, off, 64);
    if (lane == 0) out[nc] = s / (float)S;
}

// fc1(128->256)+ReLU then fc2(256->2), batch 2. One block of 256 threads.
__global__ __launch_bounds__(TPB) void fc_kernel(
    const float* __restrict__ pooled, // [2][128]
    const float* __restrict__ w1, const float* __restrict__ b1, // [256][128], [256]
    const float* __restrict__ w2, const float* __restrict__ b2, // [2][256], [2]
    float* __restrict__ out)          // [2][2]
{
    __shared__ float hbuf[2][TPB];
    const int j = threadIdx.x;
#pragma unroll
    for (int nn = 0; nn < 2; nn++) {
        float s = b1[j];
        for (int k = 0; k < 128; k++)
            s = fmaf(pooled[nn * 128 + k], w1[j * 128 + k], s);
        hbuf[nn][j] = fmaxf(s, 0.0f);
    }
    __syncthreads();
    const int wid = j >> 6, lane = j & 63;
    const int nn = wid >> 1, oo = wid & 1;
    float s = 0.0f;
    for (int k = lane; k < 256; k += 64) s += hbuf[nn][k] * w2[oo * 256 + k];
#pragma unroll
    for (int off = 32; off > 0; off >>= 1) s += __shfl_down(s, off, 64);
    if (lane == 0) out[nn * 2 + oo] = s + b2[oo];
}

extern "C" void kernel_launch(void* const* d_in, const int* in_sizes, int n_in,
                              void* d_out, int out_size, void* d_ws, size_t ws_size,
                              hipStream_t stream) {
    const float* x      = (const float*)d_in[0];
    const float* c1_w   = (const float*)d_in[1];
    const float* c1_b   = (const float*)d_in[2];
    const float* c1_kn  = (const float*)d_in[3];
    const float* c1_sw  = (const float*)d_in[4];
    const float* c1_w1  = (const float*)d_in[5];
    const float* c1_w2  = (const float*)d_in[6];
    const float* bn1_g  = (const float*)d_in[7];
    const float* bn1_b  = (const float*)d_in[8];
    const float* c2_w   = (const float*)d_in[9];
    const float* c2_b   = (const float*)d_in[10];
    const float* c2_kn  = (const float*)d_in[11];
    const float* c2_sw  = (const float*)d_in[12];
    const float* c2_w1  = (const float*)d_in[13];
    const float* c2_w2  = (const float*)d_in[14];
    const float* bn2_g  = (const float*)d_in[15];
    const float* bn2_b  = (const float*)d_in[16];
    const float* c3_w   = (const float*)d_in[17];
    const float* c3_b   = (const float*)d_in[18];
    const float* c3_kn  = (const float*)d_in[19];
    const float* c3_sw  = (const float*)d_in[20];
    const float* c3_w1  = (const float*)d_in[21];
    const float* c3_w2  = (const float*)d_in[22];
    const float* bn3_g  = (const float*)d_in[23];
    const float* bn3_b  = (const float*)d_in[24];
    const float* fc1_w  = (const float*)d_in[25];
    const float* fc1_b  = (const float*)d_in[26];
    const float* fc2_w  = (const float*)d_in[27];
    const float* fc2_b  = (const float*)d_in[28];

    float* ws = (float*)d_ws;
    float* h1     = ws;                  // 2*32*32*32*32 = 2097152 floats
    float* h2     = h1 + 2097152;        // 2*64*16*16*16 =  524288 floats
    float* h3     = h2 + 524288;         // 2*128*8*8*8   =  131072 floats
    float* pooled = h3 + 131072;         // 2*128         =     256 floats

    dim3 blk(TPB);
    // Block 1: (2,1,64,64,64) -> (2,32,32,32,32): nc=64, 32768/256=128 tiles
    spline_block_kernel<<<dim3(64, 128), blk, 0, stream>>>(
        x, c1_w, c1_b, c1_kn, c1_sw, c1_w1, c1_w2, bn1_g, bn1_b, h1,
        2, 1, 32, 64, 64, 64);
    // Block 2: (2,32,32,32,32) -> (2,64,16,16,16): nc=128, 4096/256=16 tiles
    spline_block_kernel<<<dim3(128, 16), blk, 0, stream>>>(
        h1, c2_w, c2_b, c2_kn, c2_sw, c2_w1, c2_w2, bn2_g, bn2_b, h2,
        2, 32, 64, 32, 32, 32);
    // Block 3: (2,64,16,16,16) -> (2,128,8,8,8): nc=256, 512/256=2 tiles
    spline_block_kernel<<<dim3(256, 2), blk, 0, stream>>>(
        h2, c3_w, c3_b, c3_kn, c3_sw, c3_w1, c3_w2, bn3_g, bn3_b, h3,
        2, 64, 128, 16, 16, 16);
    // Global mean pool: 256 (n,c) pairs, 512 voxels each
    mean_kernel<<<dim3(256), dim3(64), 0, stream>>>(h3, pooled, 512);
    // FC head
    fc_kernel<<<dim3(1), blk, 0, stream>>>(pooled, fc1_w, fc1_b, fc2_w, fc2_b,
                                           (float*)d_out);
}

// Round 2
// 886.576 us; speedup vs baseline: 1.2177x; 1.2177x over previous
//
#include <hip/hip_runtime.h>
#include <math.h>

#define TPB 256

// Fused: conv3d(3x3x3,pad1) -> cubic KAN spline + SiLU -> BN(eval affine) -> maxpool 2x2x2
// One thread per POOLED output voxel, G couts per thread (input window r[64]
// is reused for G couts -> 216*G FMA per 64 loads). Boundary checks hoisted
// into a single interior/exterior branch. Weights staged in LDS, read as float4.
template <int G>
__global__ __launch_bounds__(TPB, 3) void spline_block_kernel(
    const float* __restrict__ x,    // [N, Cin, D, H, W]
    const float* __restrict__ cw,   // [Cout, Cin, 3,3,3]
    const float* __restrict__ cb,   // [Cout]
    const float* __restrict__ knots,// [10]
    const float* __restrict__ sw,   // [Cout, 10]
    const float* __restrict__ w1,   // [Cout]
    const float* __restrict__ w2,   // [Cout]
    const float* __restrict__ g,    // [Cout]
    const float* __restrict__ beta, // [Cout]
    float* __restrict__ out,        // [N, Cout, D/2, H/2, W/2]
    int N, int Cin, int Cout, int D, int H, int W)
{
    // [cin][g][28] padded to 28 floats (112B) so each (cin,g) row is 16B-aligned
    __shared__ float lds_w[64 * 28];   // max Cin*G = 64 here (L2: 32*2, L3: 64*1)

    const int groups = Cout / G;
    const int grp = blockIdx.x % groups;
    const int n   = blockIdx.x / groups;
    const int c0  = grp * G;
    const int tid = threadIdx.x;

    const int nw = Cin * G * 27;
    for (int i = tid; i < nw; i += TPB) {
        const int t  = i % 27;
        const int cg = i / 27;          // cg = ci*G + gg
        const int gg = cg % G;
        const int ci = cg / G;
        lds_w[cg * 28 + t] = cw[((c0 + gg) * Cin + ci) * 27 + t];
    }
    __syncthreads();

    const int PD = D >> 1, PH = H >> 1, PW = W >> 1;
    const int total = PD * PH * PW;
    const int vox = blockIdx.y * TPB + tid;
    if (vox >= total) return;

    const int pw = vox % PW;
    int t2 = vox / PW;
    const int ph = t2 % PH;
    const int pd = t2 / PH;

    float acc[G][8];
#pragma unroll
    for (int gg = 0; gg < G; gg++) {
        const float bias = cb[c0 + gg];
#pragma unroll
        for (int i = 0; i < 8; i++) acc[gg][i] = bias;
    }

    const int d0 = 2 * pd - 1, h0 = 2 * ph - 1, w0 = 2 * pw - 1;
    const bool interior = (pd > 0) & (pd < PD - 1) &
                          (ph > 0) & (ph < PH - 1) &
                          (pw > 0) & (pw < PW - 1);

    for (int ci = 0; ci < Cin; ci++) {
        const float* xc = x + ((size_t)(n * Cin + ci)) * D * H * W;
        float r[64];
        if (interior) {
            // guard-free: 16 row bases, 4 immediate-offset loads each
#pragma unroll
            for (int dz = 0; dz < 4; dz++)
#pragma unroll
            for (int dy = 0; dy < 4; dy++) {
                const float* bp = xc + ((size_t)(d0 + dz) * H + (h0 + dy)) * W + w0;
#pragma unroll
                for (int dx = 0; dx < 4; dx++)
                    r[(dz * 4 + dy) * 4 + dx] = bp[dx];
            }
        } else {
#pragma unroll
            for (int dz = 0; dz < 4; dz++)
#pragma unroll
            for (int dy = 0; dy < 4; dy++) {
                const int dd = d0 + dz, hh = h0 + dy;
                const bool okr = ((unsigned)dd < (unsigned)D) &
                                 ((unsigned)hh < (unsigned)H);
                const float* bp = xc + ((size_t)dd * H + hh) * W + w0;
#pragma unroll
                for (int dx = 0; dx < 4; dx++) {
                    const int ww = w0 + dx;
                    const bool ok = okr & ((unsigned)ww < (unsigned)W);
                    r[(dz * 4 + dy) * 4 + dx] = ok ? bp[dx] : 0.0f;
                }
            }
        }

#pragma unroll
        for (int gg = 0; gg < G; gg++) {
            const float4* w4p = (const float4*)(lds_w + (ci * G + gg) * 28);
#pragma unroll
            for (int ch = 0; ch < 7; ch++) {
                const float4 wv = w4p[ch];
#pragma unroll
                for (int j = 0; j < 4; j++) {
                    const int tap = ch * 4 + j;
                    if (tap < 27) {
                        const float wvj = (j == 0) ? wv.x : (j == 1) ? wv.y
                                        : (j == 2) ? wv.z : wv.w;
                        const int kd = tap / 9, kh = (tap % 9) / 3, kw = tap % 3;
#pragma unroll
                        for (int od = 0; od < 2; od++)
#pragma unroll
                        for (int oh = 0; oh < 2; oh++)
#pragma unroll
                        for (int ow = 0; ow < 2; ow++)
                            acc[gg][(od * 2 + oh) * 2 + ow] =
                                fmaf(wvj,
                                     r[((od + kd) * 4 + (oh + kh)) * 4 + (ow + kw)],
                                     acc[gg][(od * 2 + oh) * 2 + ow]);
                    }
                }
            }
        }
    }

    // spline + SiLU + BN affine + max-pool over the 8 conv outputs, per cout
    float kn[10];
#pragma unroll
    for (int k = 0; k < 10; k++) kn[k] = knots[k];

#pragma unroll
    for (int gg = 0; gg < G; gg++) {
        const int c = c0 + gg;
        float sc[10];
#pragma unroll
        for (int k = 0; k < 10; k++) sc[k] = sw[c * 10 + k];
        const float W1 = w1[c], W2 = w2[c];
        const float scale = g[c] * rsqrtf(1.0f + 1e-5f);
        const float bb = beta[c];

        float m = -INFINITY;
#pragma unroll
        for (int i = 0; i < 8; i++) {
            const float y = acc[gg][i];
            float sp = 0.0f;
#pragma unroll
            for (int k = 0; k < 10; k++) {
                const float tt = fmaxf(y - kn[k], 0.0f);
                sp = fmaf(tt * tt * tt, sc[k], sp);
            }
            const float silu = y / (1.0f + __expf(-y));   // y * sigmoid(y)
            const float o = fmaf(W1 * sp + W2 * silu, scale, bb);
            m = fmaxf(m, o);
        }
        out[(size_t)(n * Cout + c) * total + vox] = m;
    }
}

// Global average pool: one wave per (n,c); S = spatial size
__global__ __launch_bounds__(64) void mean_kernel(
    const float* __restrict__ h, float* __restrict__ out, int S)
{
    const int nc = blockIdx.x;
    const int lane = threadIdx.x;
    const float* p = h + (size_t)nc * S;
    float s = 0.0f;
    for (int i = lane; i < S; i += 64) s += p[i];
#pragma unroll
    for (int off = 32; off > 0; off >>= 1) s += __shfl_down(s, off, 64);
    if (lane == 0) out[nc] = s / (float)S;
}

// fc1(128->256)+ReLU then fc2(256->2), batch 2. One block of 256 threads.
__global__ __launch_bounds__(TPB) void fc_kernel(
    const float* __restrict__ pooled, // [2][128]
    const float* __restrict__ w1, const float* __restrict__ b1, // [256][128], [256]
    const float* __restrict__ w2, const float* __restrict__ b2, // [2][256], [2]
    float* __restrict__ out)          // [2][2]
{
    __shared__ float hbuf[2][TPB];
    const int j = threadIdx.x;
#pragma unroll
    for (int nn = 0; nn < 2; nn++) {
        float s = b1[j];
        for (int k = 0; k < 128; k++)
            s = fmaf(pooled[nn * 128 + k], w1[j * 128 + k], s);
        hbuf[nn][j] = fmaxf(s, 0.0f);
    }
    __syncthreads();
    const int wid = j >> 6, lane = j & 63;
    const int nn = wid >> 1, oo = wid & 1;
    float s = 0.0f;
    for (int k = lane; k < 256; k += 64) s += hbuf[nn][k] * w2[oo * 256 + k];
#pragma unroll
    for (int off = 32; off > 0; off >>= 1) s += __shfl_down(s, off, 64);
    if (lane == 0) out[nn * 2 + oo] = s + b2[oo];
}

extern "C" void kernel_launch(void* const* d_in, const int* in_sizes, int n_in,
                              void* d_out, int out_size, void* d_ws, size_t ws_size,
                              hipStream_t stream) {
    const float* x      = (const float*)d_in[0];
    const float* c1_w   = (const float*)d_in[1];
    const float* c1_b   = (const float*)d_in[2];
    const float* c1_kn  = (const float*)d_in[3];
    const float* c1_sw  = (const float*)d_in[4];
    const float* c1_w1  = (const float*)d_in[5];
    const float* c1_w2  = (const float*)d_in[6];
    const float* bn1_g  = (const float*)d_in[7];
    const float* bn1_b  = (const float*)d_in[8];
    const float* c2_w   = (const float*)d_in[9];
    const float* c2_b   = (const float*)d_in[10];
    const float* c2_kn  = (const float*)d_in[11];
    const float* c2_sw  = (const float*)d_in[12];
    const float* c2_w1  = (const float*)d_in[13];
    const float* c2_w2  = (const float*)d_in[14];
    const float* bn2_g  = (const float*)d_in[15];
    const float* bn2_b  = (const float*)d_in[16];
    const float* c3_w   = (const float*)d_in[17];
    const float* c3_b   = (const float*)d_in[18];
    const float* c3_kn  = (const float*)d_in[19];
    const float* c3_sw  = (const float*)d_in[20];
    const float* c3_w1  = (const float*)d_in[21];
    const float* c3_w2  = (const float*)d_in[22];
    const float* bn3_g  = (const float*)d_in[23];
    const float* bn3_b  = (const float*)d_in[24];
    const float* fc1_w  = (const float*)d_in[25];
    const float* fc1_b  = (const float*)d_in[26];
    const float* fc2_w  = (const float*)d_in[27];
    const float* fc2_b  = (const float*)d_in[28];

    float* ws = (float*)d_ws;
    float* h1     = ws;                  // 2*32*32*32*32 = 2097152 floats
    float* h2     = h1 + 2097152;        // 2*64*16*16*16 =  524288 floats
    float* h3     = h2 + 524288;         // 2*128*8*8*8   =  131072 floats
    float* pooled = h3 + 131072;         // 2*128         =     256 floats

    dim3 blk(TPB);
    // L1: (2,1,64,64,64)->(2,32,32,32,32). G=4: grid.x = 2*(32/4)=16, y=32768/256=128
    spline_block_kernel<4><<<dim3(16, 128), blk, 0, stream>>>(
        x, c1_w, c1_b, c1_kn, c1_sw, c1_w1, c1_w2, bn1_g, bn1_b, h1,
        2, 1, 32, 64, 64, 64);
    // L2: (2,32,32,32,32)->(2,64,16,16,16). G=2: grid.x = 2*(64/2)=64, y=4096/256=16
    spline_block_kernel<2><<<dim3(64, 16), blk, 0, stream>>>(
        h1, c2_w, c2_b, c2_kn, c2_sw, c2_w1, c2_w2, bn2_g, bn2_b, h2,
        2, 32, 64, 32, 32, 32);
    // L3: (2,64,16,16,16)->(2,128,8,8,8). G=1: grid.x = 2*128=256, y=512/256=2
    spline_block_kernel<1><<<dim3(256, 2), blk, 0, stream>>>(
        h2, c3_w, c3_b, c3_kn, c3_sw, c3_w1, c3_w2, bn3_g, bn3_b, h3,
        2, 64, 128, 16, 16, 16);
    // Global mean pool: 256 (n,c) pairs, 512 voxels each
    mean_kernel<<<dim3(256), dim3(64), 0, stream>>>(h3, pooled, 512);
    // FC head
    fc_kernel<<<dim3(1), blk, 0, stream>>>(pooled, fc1_w, fc1_b, fc2_w, fc2_b,
                                           (float*)d_out);
}